// Round 8
// baseline (215.399 us; speedup 1.0000x reference)
//
#include <hip/hip_runtime.h>

// LowRankKVCache: out_k[..., :64] = key[..., :64]; out_k[..., 64:] = 0 (same for V).
// Pure memory-bound copy+zero, 192 MiB total traffic -> ~30 us @ 6.6 TB/s.
// Grid-stride (2048 blocks x 256), one 16B vector per iteration, nontemporal
// loads/stores (streaming, zero reuse). Native clang vector type because
// __builtin_nontemporal_* rejects HIP_vector_type structs.
using f32x4 = float __attribute__((ext_vector_type(4)));

__global__ __launch_bounds__(256) void lowrank_kv_kernel(
    const f32x4* __restrict__ k_in,
    const f32x4* __restrict__ v_in,
    f32x4* __restrict__ out,
    long long n_vec)           // f32x4 count per tensor (4,194,304)
{
    const long long stride = (long long)gridDim.x * blockDim.x;
    const long long total  = 2 * n_vec;

    for (long long i = (long long)blockIdx.x * blockDim.x + threadIdx.x;
         i < total; i += stride) {
        const bool is_k = i < n_vec;
        const long long v = is_k ? i : i - n_vec;

        f32x4 val = (f32x4)(0.f);
        if ((v & 31) < 16) {               // first 16 of 32 f32x4 per 128-f row
            const f32x4* __restrict__ src = is_k ? k_in : v_in;
            val = __builtin_nontemporal_load(&src[v]);
        }
        __builtin_nontemporal_store(val, &out[i]);
    }
}

extern "C" void kernel_launch(void* const* d_in, const int* in_sizes, int n_in,
                              void* d_out, int out_size, void* d_ws, size_t ws_size,
                              hipStream_t stream) {
    const f32x4* k_in = (const f32x4*)d_in[0];   // key_states   fp32 (4,8,4096,128)
    const f32x4* v_in = (const f32x4*)d_in[1];   // value_states fp32 (4,8,4096,128)
    // d_in[2] = cache_position — unused by the reference computation.
    f32x4* out = (f32x4*)d_out;                  // k_full ++ v_full, fp32

    long long n_vec = (long long)in_sizes[0] / 4;  // 16,777,216 / 4 = 4,194,304
    const int block = 256;
    const int grid  = 2048;                        // grid-stride: 16 iters/thread
    lowrank_kv_kernel<<<grid, block, 0, stream>>>(k_in, v_in, out, n_vec);
}